// Round 13
// baseline (345.756 us; speedup 1.0000x reference)
//
#include <hip/hip_runtime.h>
#include <hip/hip_fp16.h>

// GCN: N=100000, E=1600000, widths 128 -> 16 -> 64 -> 128 -> 1
// Round 24: R23 resubmit with INDEXING FIX in gather64s's nontemporal store:
// agg row = 64 fp16 = 128B = 16 x uint64 slots -> index must be g*16+so
// (R23 wrote g*8+so after the uint2->uint64 compile fix, halving the row
// stride: node g clobbered row g/2 -> absmax 5.6e-3 fail).
//  (1) gather64 -> 4-way CHANNEL-SHARDED (gather64s): each pass reads a 32B
//      slice (16ch fp16) per edge = one L2 sector; slice set 3.2MB < 4MiB/XCD
//      -> L2-resident. uint2 vector loads; shard = blockIdx/25000;
//      csr_src nontemporal; agg written nontemporal (uint64).
//  (2) p2 sorted-scatter: local scan of mat[b][*] -> bucket-sorted LDS
//      staging (payload+addr), sorted flush -> sector-efficient writes.
//  Frozen: MFMA gemm1/head, p3 LDS staging, g16s @2048 blocks, int4 loads.
// Pipeline: count+gemm1(MFMA) -> colscan -> p2 -> p3
//           -> gather16(r1) -> g16gemm2(r2) -> gather64s -> head(MFMA).

#define NN 100000
#define NE 1600000
#define SHIFT 8                      // 256 nodes per bucket
#define NB2 391                      // ceil(NN/256)
#define EPB 4096                     // edges per P1/P2 block
#define NBLK 391                     // ceil(NE/EPB)
#define CHUNK 7                      // ceil(NBLK/64) for colscan
#define BCAP 5120                    // LDS bucket capacity in p3 (mean 4096, sd 64)
#define G64B 25000                   // node-blocks per shard in gather64s

typedef _Float16 half8 __attribute__((ext_vector_type(8)));
typedef float f32x4 __attribute__((ext_vector_type(4)));

__device__ __forceinline__ float rdl_f(float v, int l) {
    return __int_as_float(__builtin_amdgcn_readlane(__float_as_int(v), l));
}

// unpack one half2 word, accumulate into two fp32 lanes
__device__ __forceinline__ void h2acc(unsigned u, float& a, float& b) {
    __half2 h = *reinterpret_cast<__half2*>(&u);
    float2 f = __half22float2(h);
    a += f.x; b += f.y;
}
__device__ __forceinline__ unsigned packh2(float a, float b) {
    __half2 h = __floats2half2_rn(a, b);
    return *reinterpret_cast<unsigned*>(&h);
}
__device__ __forceinline__ unsigned sc2(unsigned u, float s) {
    __half2 h = *reinterpret_cast<__half2*>(&u);
    float2 f = __half22float2(h);
    return packh2(f.x * s, f.y * s);
}

// ---------------- P1: bucket counts (blocks < NBLK) + MFMA gemm1 (rest) ----------------
__global__ __launch_bounds__(256) void count_gemm1_k(const int* __restrict__ dst,
                                                     int* __restrict__ mat,
                                                     const float* __restrict__ x,
                                                     const float* __restrict__ W1,
                                                     __half* __restrict__ A, int n) {
    __shared__ int cnt[NB2];
    __shared__ _Float16 sW1f[2048];          // 4 k-tiles x 64 lanes x 8 (frag layout)
    __shared__ unsigned sxu[4][16][68];      // per-wave fp16 x-tile, 136-half rows
    const int tid = threadIdx.x;
    if ((int)blockIdx.x < NBLK) {
        for (int i = tid; i < NB2; i += 256) cnt[i] = 0;
        __syncthreads();
        const int e0 = blockIdx.x * EPB;
        const int e1 = min(e0 + EPB, NE);
        int i = e0 + tid * 4;
        for (; i + 3 < e1; i += 1024) {
            const int4 d4 = *(const int4*)&dst[i];
            atomicAdd(&cnt[d4.x >> SHIFT], 1);
            atomicAdd(&cnt[d4.y >> SHIFT], 1);
            atomicAdd(&cnt[d4.z >> SHIFT], 1);
            atomicAdd(&cnt[d4.w >> SHIFT], 1);
        }
        for (; i < e1; ++i) atomicAdd(&cnt[dst[i] >> SHIFT], 1);
        __syncthreads();
        for (int c = tid; c < NB2; c += 256) mat[blockIdx.x * NB2 + c] = cnt[c];
        return;
    }
    const int bid = blockIdx.x - NBLK;
    const int row0 = bid * 64;
    for (int i = tid; i < 2048; i += 256) {
        const int kt = i >> 9;
        const int l = (i >> 3) & 63;
        const int j = i & 7;
        const int k = kt * 32 + ((l >> 4) << 3) + j;
        sW1f[i] = (_Float16)W1[k * 16 + (l & 15)];
    }
    const float4* in4 = (const float4*)x;
    for (int i = tid; i < 2048; i += 256) {
        const int r = i >> 5, kv = i & 31;
        const int g = row0 + r;
        float4 v = make_float4(0.f, 0.f, 0.f, 0.f);
        if (g < n) v = in4[(long)g * 32 + kv];
        unsigned* su = &sxu[r >> 4][r & 15][0];
        su[kv * 2]     = packh2(v.x, v.y);
        su[kv * 2 + 1] = packh2(v.z, v.w);
    }
    __syncthreads();
    const int w = tid >> 6, l = tid & 63;
    const int node0 = row0 + w * 16;
    f32x4 c = {0.f, 0.f, 0.f, 0.f};
#pragma unroll
    for (int kt = 0; kt < 4; ++kt) {
        const half8 a = *(const half8*)&sxu[w][l & 15][kt * 16 + ((l >> 4) << 2)];
        const half8 b = *(const half8*)&sW1f[kt * 512 + l * 8];
        c = __builtin_amdgcn_mfma_f32_16x16x32_f16(a, b, c, 0, 0, 0);
    }
#pragma unroll
    for (int i = 0; i < 4; ++i) {
        const int g = node0 + ((l >> 4) << 2) + i;
        if (g < n) A[(long)g * 16 + (l & 15)] = __float2half(c[i]);
    }
}

// ---------------- colscan: per-bucket exclusive scan over edge-blocks ----------------
__global__ __launch_bounds__(64) void colscan_k(const int* __restrict__ mat,
                                                int* __restrict__ ofsT,
                                                int* __restrict__ colTotal) {
    const int c = blockIdx.x;
    const int lane = threadIdx.x;
    int v[CHUNK];
    int s = 0;
    const int base = lane * CHUNK;
#pragma unroll
    for (int j = 0; j < CHUNK; ++j) {
        int b = base + j;
        int x_ = (b < NBLK) ? mat[b * NB2 + c] : 0;
        v[j] = s;              // local exclusive prefix
        s += x_;
    }
    int inc = s;
#pragma unroll
    for (int d = 1; d < 64; d <<= 1) {
        int t = __shfl_up(inc, d, 64);
        if (lane >= d) inc += t;
    }
    const int excl = inc - s;
#pragma unroll
    for (int j = 0; j < CHUNK; ++j) {
        int b = base + j;
        if (b < NBLK) ofsT[b * NB2 + c] = excl + v[j];
    }
    if (lane == 63) colTotal[c] = excl + s;
}

// ---------------- P2: bucket-sorted scatter via LDS staging ----------------
__global__ __launch_bounds__(512) void p2_scatter_k(const int* __restrict__ src,
                                                    const int* __restrict__ dst,
                                                    const int* __restrict__ ofsT,
                                                    const int* __restrict__ mat,
                                                    const int* __restrict__ colTotal,
                                                    int* __restrict__ bucketBase,
                                                    unsigned* __restrict__ bucketed) {
    __shared__ int wsum[8], wsum2[8];
    __shared__ int cur[NB2];                 // global run base per bucket
    __shared__ int lofs[NB2];                // local exclusive offsets
    __shared__ int lcur[NB2];                // local cursors
    __shared__ unsigned pay[EPB];
    __shared__ int gad[EPB];
    const int b = blockIdx.x;
    const int t = threadIdx.x;
    const int lane = t & 63;
    const int w = t >> 6;
    // scan 1: colTotal -> global bucket bases
    const int v = (t < NB2) ? colTotal[t] : 0;
    int x = v;
#pragma unroll
    for (int d = 1; d < 64; d <<= 1) {
        const int y = __shfl_up(x, d, 64);
        if (lane >= d) x += y;
    }
    if (lane == 63) wsum[w] = x;
    // scan 2: mat[b][*] -> local offsets
    const int mv = (t < NB2) ? mat[b * NB2 + t] : 0;
    int x2 = mv;
#pragma unroll
    for (int d = 1; d < 64; d <<= 1) {
        const int y = __shfl_up(x2, d, 64);
        if (lane >= d) x2 += y;
    }
    if (lane == 63) wsum2[w] = x2;
    __syncthreads();
    int add = 0, add2 = 0;
#pragma unroll
    for (int i = 0; i < 7; ++i)
        if (i < w) { add += wsum[i]; add2 += wsum2[i]; }
    if (t < NB2) {
        const int gbase = (x + add) - v;     // exclusive global base of bucket t
        cur[t]  = gbase + ofsT[b * NB2 + t];
        const int lx = (x2 + add2) - mv;     // exclusive local offset
        lofs[t] = lx;
        lcur[t] = lx;
    }
    if (b == 0) {
        if (t < NB2) bucketBase[t] = (x + add) - v;
        if (t == NB2) bucketBase[NB2] = NE;
    }
    __syncthreads();
    const int e0 = b * EPB;
    const int e1 = min(e0 + EPB, NE);
    const int cntT = e1 - e0;
    int i = e0 + t * 4;
    const int stride = 512 * 4;
    for (; i + 3 < e1; i += stride) {
        const int4 d4 = *(const int4*)&dst[i];
        const int4 s4 = *(const int4*)&src[i];
        const int c0 = d4.x >> SHIFT, c1 = d4.y >> SHIFT;
        const int c2 = d4.z >> SHIFT, c3 = d4.w >> SHIFT;
        const int l0 = atomicAdd(&lcur[c0], 1);
        const int l1 = atomicAdd(&lcur[c1], 1);
        const int l2 = atomicAdd(&lcur[c2], 1);
        const int l3 = atomicAdd(&lcur[c3], 1);
        pay[l0] = ((unsigned)s4.x << 8) | (unsigned)(d4.x & 255);
        pay[l1] = ((unsigned)s4.y << 8) | (unsigned)(d4.y & 255);
        pay[l2] = ((unsigned)s4.z << 8) | (unsigned)(d4.z & 255);
        pay[l3] = ((unsigned)s4.w << 8) | (unsigned)(d4.w & 255);
        gad[l0] = cur[c0] + (l0 - lofs[c0]);
        gad[l1] = cur[c1] + (l1 - lofs[c1]);
        gad[l2] = cur[c2] + (l2 - lofs[c2]);
        gad[l3] = cur[c3] + (l3 - lofs[c3]);
    }
    for (; i < e1; ++i) {
        const int d = dst[i];
        const int c = d >> SHIFT;
        const int lp = atomicAdd(&lcur[c], 1);
        pay[lp] = ((unsigned)src[i] << 8) | (unsigned)(d & 255);
        gad[lp] = cur[c] + (lp - lofs[c]);
    }
    __syncthreads();
    for (int k = t; k < cntT; k += 512) bucketed[gad[k]] = pay[k];
}

// ---------------- P3: per-bucket CSR via LDS staging + A rescale ----------------
__global__ __launch_bounds__(512) void p3_csr_k(const unsigned* __restrict__ bucketed,
                                                const int* __restrict__ bucketBase,
                                                int* __restrict__ rowptr,
                                                float* __restrict__ dinv,
                                                int* __restrict__ csr_src,
                                                __half* __restrict__ A) {
    __shared__ unsigned sEdge[BCAP];
    __shared__ int sCsr[BCAP];
    __shared__ int cnt[256];
    __shared__ int excl[256];
    __shared__ float ld[256];
    const int c = blockIdx.x;
    const int t = threadIdx.x;
    const int base = bucketBase[c];
    const int end  = bucketBase[c + 1];
    const int sz = end - base;
    if (t < 256) cnt[t] = 0;
    const bool inLds = (sz <= BCAP);
    if (inLds) {
        for (int i = t; i < sz; i += 512) sEdge[i] = bucketed[base + i];
    }
    __syncthreads();
    if (inLds) {
        for (int i = t; i < sz; i += 512) atomicAdd(&cnt[sEdge[i] & 255u], 1);
    } else {
        for (int i = base + t; i < end; i += 512) atomicAdd(&cnt[bucketed[i] & 255u], 1);
    }
    __syncthreads();
    if (t < 256) excl[t] = cnt[t];
    __syncthreads();
    for (int off = 1; off < 256; off <<= 1) {
        int a = (t < 256 && t >= off) ? excl[t - off] : 0;
        __syncthreads();
        if (t < 256) excl[t] += a;
        __syncthreads();
    }
    const int node0 = c << SHIFT;
    if (t < 256) {
        const int node = node0 + t;
        const int ex = excl[t] - cnt[t];
        if (node < NN) {
            rowptr[node] = base + ex;
            const float dv = rsqrtf((float)cnt[t] + 1.0f);  // +1 self loop
            dinv[node] = dv;
            ld[t] = dv;
        }
        excl[t] = ex;  // becomes the fill cursor
    }
    if (c == NB2 - 1 && t == 0) rowptr[NN] = NE;
    __syncthreads();
    if (inLds) {
        for (int i = t; i < sz; i += 512) {
            const unsigned p = sEdge[i];
            const int pos = atomicAdd(&excl[p & 255u], 1);
            sCsr[pos] = (int)(p >> 8);
        }
        __syncthreads();
        for (int i = t; i < sz; i += 512) csr_src[base + i] = sCsr[i];
    } else {
        for (int i = base + t; i < end; i += 512) {
            const unsigned p = bucketed[i];
            const int pos = atomicAdd(&excl[p & 255u], 1);
            csr_src[base + pos] = (int)(p >> 8);
        }
    }
    {
        const int node = node0 + (t >> 1);
        if (node < NN) {
            const float dv = ld[t >> 1];
            uint4* p = (uint4*)(A + (long)node * 16 + (t & 1) * 8);
            uint4 q = *p;
            q.x = sc2(q.x, dv); q.y = sc2(q.y, dv);
            q.z = sc2(q.z, dv); q.w = sc2(q.w, dv);
            *p = q;
        }
    }
}

// ---------------- pull-gather, 16 ch fp16 (persistent): B = dinv*relu(dg*(sum A)+b1) ----
__global__ __launch_bounds__(256) void gather16h_k(const int* __restrict__ rowptr,
                                                   const int* __restrict__ csr_src,
                                                   const float* __restrict__ dinv,
                                                   const __half* __restrict__ hs,
                                                   const float* __restrict__ bias,
                                                   __half* __restrict__ outp, int n) {
    const int lane = threadIdx.x & 63;
    const int wid0 = blockIdx.x * 4 + (threadIdx.x >> 6);
    const int nWaves = gridDim.x * 4;
    const int q = lane & 3;                 // uint2 chunk within 16-ch row
    const int sub = lane >> 2;              // edge subgroup 0..15
    const uint2* h2p = (const uint2*)hs;
    const float4 b = ((const float4*)bias)[q];
    for (int g = wid0; g < n; g += nWaves) {
        const float dg = dinv[g];
        const int beg = rowptr[g], end = rowptr[g + 1];
        float a0 = 0.f, a1 = 0.f, a2 = 0.f, a3 = 0.f;
        if (sub == 0) {                      // self term
            uint2 v = h2p[(long)g * 4 + q];
            h2acc(v.x, a0, a1); h2acc(v.y, a2, a3);
        }
        for (int j0 = beg; j0 < end; j0 += 16) {
            int idx = j0 + sub;
            if (idx < end) {
                const int s = csr_src[idx];
                uint2 v = h2p[(long)s * 4 + q];
                h2acc(v.x, a0, a1); h2acc(v.y, a2, a3);
            }
        }
#pragma unroll
        for (int m = 4; m <= 32; m <<= 1) {
            a0 += __shfl_xor(a0, m, 64);
            a1 += __shfl_xor(a1, m, 64);
            a2 += __shfl_xor(a2, m, 64);
            a3 += __shfl_xor(a3, m, 64);
        }
        if (sub == 0) {
            float v0 = fmaxf(fmaf(dg, a0, b.x), 0.0f) * dg;
            float v1 = fmaxf(fmaf(dg, a1, b.y), 0.0f) * dg;
            float v2 = fmaxf(fmaf(dg, a2, b.z), 0.0f) * dg;
            float v3 = fmaxf(fmaf(dg, a3, b.w), 0.0f) * dg;
            uint2 w;
            w.x = packh2(v0, v1);
            w.y = packh2(v2, v3);
            ((uint2*)outp)[(long)g * 4 + q] = w;
        }
    }
}

// ---------------- fused gather16 + gemm2: C = dinv*relu(dg*(sum B)@W2 + b2), fp16 out ----
__global__ __launch_bounds__(256) void g16gemm2h_k(const int* __restrict__ rowptr,
                                                   const int* __restrict__ csr_src,
                                                   const float* __restrict__ dinv,
                                                   const __half* __restrict__ hs,
                                                   const float* __restrict__ W2,
                                                   const float* __restrict__ b2,
                                                   __half* __restrict__ outp, int n) {
    const int lane = threadIdx.x & 63;
    const int wid = blockIdx.x * 4 + (threadIdx.x >> 6);
    const int nWaves = gridDim.x * 4;
    float w2[16];
#pragma unroll
    for (int k = 0; k < 16; ++k) w2[k] = W2[k * 64 + lane];
    const float bm = b2[lane];
    const int q = lane & 3;
    const int sub = lane >> 2;
    const uint2* h2p = (const uint2*)hs;
    for (int g = wid; g < n; g += nWaves) {
        const float dg = dinv[g];
        const int beg = rowptr[g], end = rowptr[g + 1];
        float a0 = 0.f, a1 = 0.f, a2 = 0.f, a3 = 0.f;
        if (sub == 0) {                      // self term
            uint2 v = h2p[(long)g * 4 + q];
            h2acc(v.x, a0, a1); h2acc(v.y, a2, a3);
        }
        for (int j0 = beg; j0 < end; j0 += 16) {
            int idx = j0 + sub;
            if (idx < end) {
                const int s = csr_src[idx];
                uint2 v = h2p[(long)s * 4 + q];
                h2acc(v.x, a0, a1); h2acc(v.y, a2, a3);
            }
        }
#pragma unroll
        for (int m = 4; m <= 32; m <<= 1) {
            a0 += __shfl_xor(a0, m, 64);
            a1 += __shfl_xor(a1, m, 64);
            a2 += __shfl_xor(a2, m, 64);
            a3 += __shfl_xor(a3, m, 64);
        }
        float t = 0.0f;
#pragma unroll
        for (int ql = 0; ql < 4; ++ql) {
            t = fmaf(rdl_f(a0, ql), w2[4 * ql + 0], t);
            t = fmaf(rdl_f(a1, ql), w2[4 * ql + 1], t);
            t = fmaf(rdl_f(a2, ql), w2[4 * ql + 2], t);
            t = fmaf(rdl_f(a3, ql), w2[4 * ql + 3], t);
        }
        float r = fmaxf(fmaf(dg, t, bm), 0.0f);   // dg*(sum)@W2 + b2, relu
        outp[(long)g * 64 + lane] = __float2half(r * dg);  // pre-scaled fp16
    }
}

// ---------------- 4-way channel-sharded gather64: agg = dg * sum C ----------------
// shard = blockIdx/G64B (dispatch-ordered: concurrent blocks share a slice).
// Per edge: one 32B slice read (uint2 x 4 lanes); slice set 3.2MB -> XCD-L2
// resident. csr_src nontemporal; agg written nontemporal as uint64
// (row = 128B = 16 uint64 slots -> index g*16+so).
__global__ __launch_bounds__(256) void gather64s_k(const int* __restrict__ rowptr,
                                                   const int* __restrict__ csr_src,
                                                   const float* __restrict__ dinv,
                                                   const __half* __restrict__ hs,
                                                   __half* __restrict__ outp, int n) {
    const int shard = blockIdx.x / G64B;    // 0..3
    const int nb = blockIdx.x - shard * G64B;
    const int g = (nb * 256 + threadIdx.x) >> 6;
    if (g >= n) return;
    const int lane = threadIdx.x & 63;
    const int q = lane & 3;                 // uint2 chunk within 32B slice
    const int sub = lane >> 2;              // edge subgroup 0..15
    const float dg = dinv[g];
    const int beg = rowptr[g], end = rowptr[g + 1];
    const uint2* h2 = (const uint2*)hs;     // row = 16 uint2 (64ch fp16)
    const int so = shard * 4 + q;           // slice offset within row
    float a0 = 0.f, a1 = 0.f, a2 = 0.f, a3 = 0.f;
    if (sub == 0) {                          // self term
        const uint2 v = h2[(long)g * 16 + so];
        h2acc(v.x, a0, a1); h2acc(v.y, a2, a3);
    }
    int j0 = beg;
    for (; j0 + 32 <= end; j0 += 32) {
        const int s0 = __builtin_nontemporal_load(&csr_src[j0 + sub]);
        const int s1 = __builtin_nontemporal_load(&csr_src[j0 + 16 + sub]);
        const uint2 v0 = h2[(long)s0 * 16 + so];
        const uint2 v1 = h2[(long)s1 * 16 + so];
        h2acc(v0.x, a0, a1); h2acc(v0.y, a2, a3);
        h2acc(v1.x, a0, a1); h2acc(v1.y, a2, a3);
    }
    for (; j0 < end; j0 += 16) {
        const int idx = j0 + sub;
        if (idx < end) {
            const int s = __builtin_nontemporal_load(&csr_src[idx]);
            const uint2 v = h2[(long)s * 16 + so];
            h2acc(v.x, a0, a1); h2acc(v.y, a2, a3);
        }
    }
#pragma unroll
    for (int m = 4; m <= 32; m <<= 1) {
        a0 += __shfl_xor(a0, m, 64);
        a1 += __shfl_xor(a1, m, 64);
        a2 += __shfl_xor(a2, m, 64);
        a3 += __shfl_xor(a3, m, 64);
    }
    if (sub == 0) {
        const unsigned wlo = packh2(a0 * dg, a1 * dg);
        const unsigned whi = packh2(a2 * dg, a3 * dg);
        const unsigned long long wv =
            ((unsigned long long)whi << 32) | (unsigned long long)wlo;
        __builtin_nontemporal_store(
            wv, &((unsigned long long*)outp)[(long)g * 16 + so]);
    }
}

// ---------------- MFMA head: out = relu(agg@W3 + b3).Wfc + bfc ----------------
__global__ __launch_bounds__(256) void head_mfma_k(const __half* __restrict__ agg,
                                                   const float* __restrict__ W3,
                                                   const float* __restrict__ b3,
                                                   const float* __restrict__ Wfc,
                                                   const float* __restrict__ bfc,
                                                   float* __restrict__ out, int n) {
    __shared__ _Float16 sWf[8192];           // 16 KB, frag-layout
    const int tid = threadIdx.x;
    for (int i = tid; i < 8192; i += 256) {
        const int j = i & 7;
        const int l = (i >> 3) & 63;
        const int th = i >> 9;
        const int k = (th & 1) * 32 + ((l >> 4) << 3) + j;
        const int nn = (th >> 1) * 16 + (l & 15);
        sWf[i] = (_Float16)W3[k * 128 + nn];
    }
    __syncthreads();
    const int lane = tid & 63;
    const int wid = blockIdx.x * 4 + (tid >> 6);
    const int nWaves = gridDim.x * 4;
    const int col = lane & 15;
    const int kg = lane >> 4;
    half8 wf[16];
#pragma unroll
    for (int q2 = 0; q2 < 16; ++q2)
        wf[q2] = *((const half8*)&sWf[(q2 * 64 + lane) * 8]);
    float b3v[8], wfv[8];
#pragma unroll
    for (int t = 0; t < 8; ++t) {
        b3v[t] = b3[t * 16 + col];
        wfv[t] = Wfc[t * 16 + col];
    }
    const float bb = bfc[0];
    const int nTiles = n >> 4;               // 6250, exact
    union { uint4 u; half8 h; } cva, cvb;
    for (int tile = wid; tile < nTiles; tile += nWaves) {
        const int node0 = tile << 4;
        const uint4* rowp = (const uint4*)(agg + (long)(node0 + col) * 64);
        cva.u = rowp[kg];                     // k = kg*8 .. +8   (half 0)
        cvb.u = rowp[4 + kg];                 // k = 32 + kg*8..  (half 1)
        const half8 a0 = cva.h, a1 = cvb.h;
        f32x4 c[8];
#pragma unroll
        for (int t = 0; t < 8; ++t) {
            f32x4 z = {0.f, 0.f, 0.f, 0.f};
            c[t] = __builtin_amdgcn_mfma_f32_16x16x32_f16(a0, wf[t * 2], z, 0, 0, 0);
            c[t] = __builtin_amdgcn_mfma_f32_16x16x32_f16(a1, wf[t * 2 + 1], c[t], 0, 0, 0);
        }
        float s0 = 0.f, s1 = 0.f, s2 = 0.f, s3 = 0.f;
#pragma unroll
        for (int t = 0; t < 8; ++t) {
            s0 += fmaxf(c[t][0] + b3v[t], 0.f) * wfv[t];
            s1 += fmaxf(c[t][1] + b3v[t], 0.f) * wfv[t];
            s2 += fmaxf(c[t][2] + b3v[t], 0.f) * wfv[t];
            s3 += fmaxf(c[t][3] + b3v[t], 0.f) * wfv[t];
        }
#pragma unroll
        for (int m = 1; m <= 8; m <<= 1) {
            s0 += __shfl_xor(s0, m, 64);
            s1 += __shfl_xor(s1, m, 64);
            s2 += __shfl_xor(s2, m, 64);
            s3 += __shfl_xor(s3, m, 64);
        }
        if (col == 0) {
            const int nb = node0 + kg * 4;
            out[nb]     = s0 + bb;
            out[nb + 1] = s1 + bb;
            out[nb + 2] = s2 + bb;
            out[nb + 3] = s3 + bb;
        }
    }
}

extern "C" void kernel_launch(void* const* d_in, const int* in_sizes, int n_in,
                              void* d_out, int out_size, void* d_ws, size_t ws_size,
                              hipStream_t stream) {
    const float* x    = (const float*)d_in[0];
    const int*   ei   = (const int*)d_in[1];       // [2,E]: src = ei, dst = ei+E
    const float* W1   = (const float*)d_in[2];
    const float* b1   = (const float*)d_in[3];
    const float* W2   = (const float*)d_in[4];
    const float* b2   = (const float*)d_in[5];
    const float* W3   = (const float*)d_in[6];
    const float* b3   = (const float*)d_in[7];
    const float* Wfc  = (const float*)d_in[8];
    const float* bfc  = (const float*)d_in[9];
    float* out = (float*)d_out;

    const int* src = ei;
    const int* dst = ei + NE;

    // workspace layout (16B-aligned offsets; 4B units):
    // dinv[N] | rowptr[N+8] | mat[NBLK*NB2] | ofsT[NBLK*NB2] | colTotal[512]
    // | bucketBase[512] | csr_src[E+64] | bucketed[E] u32
    // | A_h[16N] fp16 | B_h[16N] fp16 | C_h[64N] fp16 | agg_h[64N] fp16
    float* dinv        = (float*)d_ws;
    int*   rowptr      = (int*)(dinv + NN);
    int*   mat         = rowptr + NN + 8;
    int*   ofsT        = mat + NBLK * NB2 + 4;
    int*   colTotal    = ofsT + NBLK * NB2 + 4;
    int*   bucketBase  = colTotal + 512;
    int*   csr_src     = bucketBase + 512;
    unsigned* bucketed = (unsigned*)(csr_src + NE + 64);
    __half* A_h        = (__half*)(bucketed + NE);
    __half* B_h        = A_h + (long)NN * 16;
    __half* C_h        = B_h + (long)NN * 16;
    __half* agg_h      = C_h + (long)NN * 64;

    const int T = 256;

    // ---- CSR build (atomic-free) + MFMA gemm1 overlapped ----
    const int gemmBlocks = (NN + 63) / 64;             // 1563
    count_gemm1_k<<<NBLK + gemmBlocks, T, 0, stream>>>(dst, mat, x, W1, A_h, NN);
    colscan_k<<<NB2, 64, 0, stream>>>(mat, ofsT, colTotal);
    p2_scatter_k<<<NBLK, 512, 0, stream>>>(src, dst, ofsT, mat, colTotal, bucketBase, bucketed);
    p3_csr_k<<<NB2, 512, 0, stream>>>(bucketed, bucketBase, rowptr, dinv, csr_src, A_h);

    // ---- B = dinv * relu(dg*(sum A) + b1)  (pre-scaled r1, 16ch fp16) ----
    gather16h_k<<<2048, T, 0, stream>>>(rowptr, csr_src, dinv, A_h, b1, B_h, NN);
    // ---- C = dinv * relu(dg*(sum B)@W2 + b2)  (pre-scaled r2, 64ch fp16) ----
    g16gemm2h_k<<<2048, T, 0, stream>>>(rowptr, csr_src, dinv, B_h, W2, b2, C_h, NN);
    // ---- agg(64ch fp16) = dg * sum C  (4-way channel-sharded) ----
    gather64s_k<<<4 * G64B, T, 0, stream>>>(rowptr, csr_src, dinv, C_h, agg_h, NN);
    // ---- head: out = relu(agg@W3 + b3).Wfc + bfc  (MFMA) ----
    head_mfma_k<<<256, T, 0, stream>>>(agg_h, W3, b3, Wfc, bfc, out, NN);
}

// Round 14
// 244.886 us; speedup vs baseline: 1.4119x; 1.4119x over previous
//
#include <hip/hip_runtime.h>
#include <hip/hip_fp16.h>

// GCN: N=100000, E=1600000, widths 128 -> 16 -> 64 -> 128 -> 1
// Round 25 (from 345.8us R24 / 248.8us R21 best):
//  POST-MORTEM R24: channel-sharding REFUTED by counters -- FETCH 156->403MB
//  (= 4 passes x E x 64B: L2-fill granularity is 64B, so a 32B slice read
//  still pulls a 64B sector and the slice set spans the full 12.8MB of rows
//  at line granularity -> never L2-resident; 4x traversal multiplied raw
//  traffic). Sharding closed permanently (2 distinct failure mechanisms).
//  KEEP R24's p2 sorted-scatter + bucketBase-from-p2 (ledger: rest of R24
//  was ~ -6us vs R21). REVERT gather64 to R16-exact block-per-node kernel
//  (proven 49.7us / 156MB / ~3.5TB/s -- its L2-miss structural floor).
// Pipeline: count+gemm1(MFMA) -> colscan -> p2 -> p3
//           -> gather16(r1) -> g16gemm2(r2) -> gather64 -> head(MFMA).

#define NN 100000
#define NE 1600000
#define SHIFT 8                      // 256 nodes per bucket
#define NB2 391                      // ceil(NN/256)
#define EPB 4096                     // edges per P1/P2 block
#define NBLK 391                     // ceil(NE/EPB)
#define CHUNK 7                      // ceil(NBLK/64) for colscan
#define BCAP 5120                    // LDS bucket capacity in p3 (mean 4096, sd 64)

typedef _Float16 half8 __attribute__((ext_vector_type(8)));
typedef float f32x4 __attribute__((ext_vector_type(4)));

__device__ __forceinline__ float rdl_f(float v, int l) {
    return __int_as_float(__builtin_amdgcn_readlane(__float_as_int(v), l));
}

// unpack one half2 word, accumulate into two fp32 lanes
__device__ __forceinline__ void h2acc(unsigned u, float& a, float& b) {
    __half2 h = *reinterpret_cast<__half2*>(&u);
    float2 f = __half22float2(h);
    a += f.x; b += f.y;
}
__device__ __forceinline__ unsigned packh2(float a, float b) {
    __half2 h = __floats2half2_rn(a, b);
    return *reinterpret_cast<unsigned*>(&h);
}
__device__ __forceinline__ unsigned sc2(unsigned u, float s) {
    __half2 h = *reinterpret_cast<__half2*>(&u);
    float2 f = __half22float2(h);
    return packh2(f.x * s, f.y * s);
}

// ---------------- P1: bucket counts (blocks < NBLK) + MFMA gemm1 (rest) ----------------
__global__ __launch_bounds__(256) void count_gemm1_k(const int* __restrict__ dst,
                                                     int* __restrict__ mat,
                                                     const float* __restrict__ x,
                                                     const float* __restrict__ W1,
                                                     __half* __restrict__ A, int n) {
    __shared__ int cnt[NB2];
    __shared__ _Float16 sW1f[2048];          // 4 k-tiles x 64 lanes x 8 (frag layout)
    __shared__ unsigned sxu[4][16][68];      // per-wave fp16 x-tile, 136-half rows
    const int tid = threadIdx.x;
    if ((int)blockIdx.x < NBLK) {
        for (int i = tid; i < NB2; i += 256) cnt[i] = 0;
        __syncthreads();
        const int e0 = blockIdx.x * EPB;
        const int e1 = min(e0 + EPB, NE);
        int i = e0 + tid * 4;
        for (; i + 3 < e1; i += 1024) {
            const int4 d4 = *(const int4*)&dst[i];
            atomicAdd(&cnt[d4.x >> SHIFT], 1);
            atomicAdd(&cnt[d4.y >> SHIFT], 1);
            atomicAdd(&cnt[d4.z >> SHIFT], 1);
            atomicAdd(&cnt[d4.w >> SHIFT], 1);
        }
        for (; i < e1; ++i) atomicAdd(&cnt[dst[i] >> SHIFT], 1);
        __syncthreads();
        for (int c = tid; c < NB2; c += 256) mat[blockIdx.x * NB2 + c] = cnt[c];
        return;
    }
    const int bid = blockIdx.x - NBLK;
    const int row0 = bid * 64;
    for (int i = tid; i < 2048; i += 256) {
        const int kt = i >> 9;
        const int l = (i >> 3) & 63;
        const int j = i & 7;
        const int k = kt * 32 + ((l >> 4) << 3) + j;
        sW1f[i] = (_Float16)W1[k * 16 + (l & 15)];
    }
    const float4* in4 = (const float4*)x;
    for (int i = tid; i < 2048; i += 256) {
        const int r = i >> 5, kv = i & 31;
        const int g = row0 + r;
        float4 v = make_float4(0.f, 0.f, 0.f, 0.f);
        if (g < n) v = in4[(long)g * 32 + kv];
        unsigned* su = &sxu[r >> 4][r & 15][0];
        su[kv * 2]     = packh2(v.x, v.y);
        su[kv * 2 + 1] = packh2(v.z, v.w);
    }
    __syncthreads();
    const int w = tid >> 6, l = tid & 63;
    const int node0 = row0 + w * 16;
    f32x4 c = {0.f, 0.f, 0.f, 0.f};
#pragma unroll
    for (int kt = 0; kt < 4; ++kt) {
        const half8 a = *(const half8*)&sxu[w][l & 15][kt * 16 + ((l >> 4) << 2)];
        const half8 b = *(const half8*)&sW1f[kt * 512 + l * 8];
        c = __builtin_amdgcn_mfma_f32_16x16x32_f16(a, b, c, 0, 0, 0);
    }
#pragma unroll
    for (int i = 0; i < 4; ++i) {
        const int g = node0 + ((l >> 4) << 2) + i;
        if (g < n) A[(long)g * 16 + (l & 15)] = __float2half(c[i]);
    }
}

// ---------------- colscan: per-bucket exclusive scan over edge-blocks ----------------
__global__ __launch_bounds__(64) void colscan_k(const int* __restrict__ mat,
                                                int* __restrict__ ofsT,
                                                int* __restrict__ colTotal) {
    const int c = blockIdx.x;
    const int lane = threadIdx.x;
    int v[CHUNK];
    int s = 0;
    const int base = lane * CHUNK;
#pragma unroll
    for (int j = 0; j < CHUNK; ++j) {
        int b = base + j;
        int x_ = (b < NBLK) ? mat[b * NB2 + c] : 0;
        v[j] = s;              // local exclusive prefix
        s += x_;
    }
    int inc = s;
#pragma unroll
    for (int d = 1; d < 64; d <<= 1) {
        int t = __shfl_up(inc, d, 64);
        if (lane >= d) inc += t;
    }
    const int excl = inc - s;
#pragma unroll
    for (int j = 0; j < CHUNK; ++j) {
        int b = base + j;
        if (b < NBLK) ofsT[b * NB2 + c] = excl + v[j];
    }
    if (lane == 63) colTotal[c] = excl + s;
}

// ---------------- P2: bucket-sorted scatter via LDS staging ----------------
__global__ __launch_bounds__(512) void p2_scatter_k(const int* __restrict__ src,
                                                    const int* __restrict__ dst,
                                                    const int* __restrict__ ofsT,
                                                    const int* __restrict__ mat,
                                                    const int* __restrict__ colTotal,
                                                    int* __restrict__ bucketBase,
                                                    unsigned* __restrict__ bucketed) {
    __shared__ int wsum[8], wsum2[8];
    __shared__ int cur[NB2];                 // global run base per bucket
    __shared__ int lofs[NB2];                // local exclusive offsets
    __shared__ int lcur[NB2];                // local cursors
    __shared__ unsigned pay[EPB];
    __shared__ int gad[EPB];
    const int b = blockIdx.x;
    const int t = threadIdx.x;
    const int lane = t & 63;
    const int w = t >> 6;
    // scan 1: colTotal -> global bucket bases
    const int v = (t < NB2) ? colTotal[t] : 0;
    int x = v;
#pragma unroll
    for (int d = 1; d < 64; d <<= 1) {
        const int y = __shfl_up(x, d, 64);
        if (lane >= d) x += y;
    }
    if (lane == 63) wsum[w] = x;
    // scan 2: mat[b][*] -> local offsets
    const int mv = (t < NB2) ? mat[b * NB2 + t] : 0;
    int x2 = mv;
#pragma unroll
    for (int d = 1; d < 64; d <<= 1) {
        const int y = __shfl_up(x2, d, 64);
        if (lane >= d) x2 += y;
    }
    if (lane == 63) wsum2[w] = x2;
    __syncthreads();
    int add = 0, add2 = 0;
#pragma unroll
    for (int i = 0; i < 7; ++i)
        if (i < w) { add += wsum[i]; add2 += wsum2[i]; }
    if (t < NB2) {
        const int gbase = (x + add) - v;     // exclusive global base of bucket t
        cur[t]  = gbase + ofsT[b * NB2 + t];
        const int lx = (x2 + add2) - mv;     // exclusive local offset
        lofs[t] = lx;
        lcur[t] = lx;
    }
    if (b == 0) {
        if (t < NB2) bucketBase[t] = (x + add) - v;
        if (t == NB2) bucketBase[NB2] = NE;
    }
    __syncthreads();
    const int e0 = b * EPB;
    const int e1 = min(e0 + EPB, NE);
    const int cntT = e1 - e0;
    int i = e0 + t * 4;
    const int stride = 512 * 4;
    for (; i + 3 < e1; i += stride) {
        const int4 d4 = *(const int4*)&dst[i];
        const int4 s4 = *(const int4*)&src[i];
        const int c0 = d4.x >> SHIFT, c1 = d4.y >> SHIFT;
        const int c2 = d4.z >> SHIFT, c3 = d4.w >> SHIFT;
        const int l0 = atomicAdd(&lcur[c0], 1);
        const int l1 = atomicAdd(&lcur[c1], 1);
        const int l2 = atomicAdd(&lcur[c2], 1);
        const int l3 = atomicAdd(&lcur[c3], 1);
        pay[l0] = ((unsigned)s4.x << 8) | (unsigned)(d4.x & 255);
        pay[l1] = ((unsigned)s4.y << 8) | (unsigned)(d4.y & 255);
        pay[l2] = ((unsigned)s4.z << 8) | (unsigned)(d4.z & 255);
        pay[l3] = ((unsigned)s4.w << 8) | (unsigned)(d4.w & 255);
        gad[l0] = cur[c0] + (l0 - lofs[c0]);
        gad[l1] = cur[c1] + (l1 - lofs[c1]);
        gad[l2] = cur[c2] + (l2 - lofs[c2]);
        gad[l3] = cur[c3] + (l3 - lofs[c3]);
    }
    for (; i < e1; ++i) {
        const int d = dst[i];
        const int c = d >> SHIFT;
        const int lp = atomicAdd(&lcur[c], 1);
        pay[lp] = ((unsigned)src[i] << 8) | (unsigned)(d & 255);
        gad[lp] = cur[c] + (lp - lofs[c]);
    }
    __syncthreads();
    for (int k = t; k < cntT; k += 512) bucketed[gad[k]] = pay[k];
}

// ---------------- P3: per-bucket CSR via LDS staging + A rescale ----------------
__global__ __launch_bounds__(512) void p3_csr_k(const unsigned* __restrict__ bucketed,
                                                const int* __restrict__ bucketBase,
                                                int* __restrict__ rowptr,
                                                float* __restrict__ dinv,
                                                int* __restrict__ csr_src,
                                                __half* __restrict__ A) {
    __shared__ unsigned sEdge[BCAP];
    __shared__ int sCsr[BCAP];
    __shared__ int cnt[256];
    __shared__ int excl[256];
    __shared__ float ld[256];
    const int c = blockIdx.x;
    const int t = threadIdx.x;
    const int base = bucketBase[c];
    const int end  = bucketBase[c + 1];
    const int sz = end - base;
    if (t < 256) cnt[t] = 0;
    const bool inLds = (sz <= BCAP);
    if (inLds) {
        for (int i = t; i < sz; i += 512) sEdge[i] = bucketed[base + i];
    }
    __syncthreads();
    if (inLds) {
        for (int i = t; i < sz; i += 512) atomicAdd(&cnt[sEdge[i] & 255u], 1);
    } else {
        for (int i = base + t; i < end; i += 512) atomicAdd(&cnt[bucketed[i] & 255u], 1);
    }
    __syncthreads();
    if (t < 256) excl[t] = cnt[t];
    __syncthreads();
    for (int off = 1; off < 256; off <<= 1) {
        int a = (t < 256 && t >= off) ? excl[t - off] : 0;
        __syncthreads();
        if (t < 256) excl[t] += a;
        __syncthreads();
    }
    const int node0 = c << SHIFT;
    if (t < 256) {
        const int node = node0 + t;
        const int ex = excl[t] - cnt[t];
        if (node < NN) {
            rowptr[node] = base + ex;
            const float dv = rsqrtf((float)cnt[t] + 1.0f);  // +1 self loop
            dinv[node] = dv;
            ld[t] = dv;
        }
        excl[t] = ex;  // becomes the fill cursor
    }
    if (c == NB2 - 1 && t == 0) rowptr[NN] = NE;
    __syncthreads();
    if (inLds) {
        for (int i = t; i < sz; i += 512) {
            const unsigned p = sEdge[i];
            const int pos = atomicAdd(&excl[p & 255u], 1);
            sCsr[pos] = (int)(p >> 8);
        }
        __syncthreads();
        for (int i = t; i < sz; i += 512) csr_src[base + i] = sCsr[i];
    } else {
        for (int i = base + t; i < end; i += 512) {
            const unsigned p = bucketed[i];
            const int pos = atomicAdd(&excl[p & 255u], 1);
            csr_src[base + pos] = (int)(p >> 8);
        }
    }
    {
        const int node = node0 + (t >> 1);
        if (node < NN) {
            const float dv = ld[t >> 1];
            uint4* p = (uint4*)(A + (long)node * 16 + (t & 1) * 8);
            uint4 q = *p;
            q.x = sc2(q.x, dv); q.y = sc2(q.y, dv);
            q.z = sc2(q.z, dv); q.w = sc2(q.w, dv);
            *p = q;
        }
    }
}

// ---------------- pull-gather, 16 ch fp16 (persistent): B = dinv*relu(dg*(sum A)+b1) ----
__global__ __launch_bounds__(256) void gather16h_k(const int* __restrict__ rowptr,
                                                   const int* __restrict__ csr_src,
                                                   const float* __restrict__ dinv,
                                                   const __half* __restrict__ hs,
                                                   const float* __restrict__ bias,
                                                   __half* __restrict__ outp, int n) {
    const int lane = threadIdx.x & 63;
    const int wid0 = blockIdx.x * 4 + (threadIdx.x >> 6);
    const int nWaves = gridDim.x * 4;
    const int q = lane & 3;                 // uint2 chunk within 16-ch row
    const int sub = lane >> 2;              // edge subgroup 0..15
    const uint2* h2p = (const uint2*)hs;
    const float4 b = ((const float4*)bias)[q];
    for (int g = wid0; g < n; g += nWaves) {
        const float dg = dinv[g];
        const int beg = rowptr[g], end = rowptr[g + 1];
        float a0 = 0.f, a1 = 0.f, a2 = 0.f, a3 = 0.f;
        if (sub == 0) {                      // self term
            uint2 v = h2p[(long)g * 4 + q];
            h2acc(v.x, a0, a1); h2acc(v.y, a2, a3);
        }
        for (int j0 = beg; j0 < end; j0 += 16) {
            int idx = j0 + sub;
            if (idx < end) {
                const int s = csr_src[idx];
                uint2 v = h2p[(long)s * 4 + q];
                h2acc(v.x, a0, a1); h2acc(v.y, a2, a3);
            }
        }
#pragma unroll
        for (int m = 4; m <= 32; m <<= 1) {
            a0 += __shfl_xor(a0, m, 64);
            a1 += __shfl_xor(a1, m, 64);
            a2 += __shfl_xor(a2, m, 64);
            a3 += __shfl_xor(a3, m, 64);
        }
        if (sub == 0) {
            float v0 = fmaxf(fmaf(dg, a0, b.x), 0.0f) * dg;
            float v1 = fmaxf(fmaf(dg, a1, b.y), 0.0f) * dg;
            float v2 = fmaxf(fmaf(dg, a2, b.z), 0.0f) * dg;
            float v3 = fmaxf(fmaf(dg, a3, b.w), 0.0f) * dg;
            uint2 w;
            w.x = packh2(v0, v1);
            w.y = packh2(v2, v3);
            ((uint2*)outp)[(long)g * 4 + q] = w;
        }
    }
}

// ---------------- fused gather16 + gemm2: C = dinv*relu(dg*(sum B)@W2 + b2), fp16 out ----
__global__ __launch_bounds__(256) void g16gemm2h_k(const int* __restrict__ rowptr,
                                                   const int* __restrict__ csr_src,
                                                   const float* __restrict__ dinv,
                                                   const __half* __restrict__ hs,
                                                   const float* __restrict__ W2,
                                                   const float* __restrict__ b2,
                                                   __half* __restrict__ outp, int n) {
    const int lane = threadIdx.x & 63;
    const int wid = blockIdx.x * 4 + (threadIdx.x >> 6);
    const int nWaves = gridDim.x * 4;
    float w2[16];
#pragma unroll
    for (int k = 0; k < 16; ++k) w2[k] = W2[k * 64 + lane];
    const float bm = b2[lane];
    const int q = lane & 3;
    const int sub = lane >> 2;
    const uint2* h2p = (const uint2*)hs;
    for (int g = wid; g < n; g += nWaves) {
        const float dg = dinv[g];
        const int beg = rowptr[g], end = rowptr[g + 1];
        float a0 = 0.f, a1 = 0.f, a2 = 0.f, a3 = 0.f;
        if (sub == 0) {                      // self term
            uint2 v = h2p[(long)g * 4 + q];
            h2acc(v.x, a0, a1); h2acc(v.y, a2, a3);
        }
        for (int j0 = beg; j0 < end; j0 += 16) {
            int idx = j0 + sub;
            if (idx < end) {
                const int s = csr_src[idx];
                uint2 v = h2p[(long)s * 4 + q];
                h2acc(v.x, a0, a1); h2acc(v.y, a2, a3);
            }
        }
#pragma unroll
        for (int m = 4; m <= 32; m <<= 1) {
            a0 += __shfl_xor(a0, m, 64);
            a1 += __shfl_xor(a1, m, 64);
            a2 += __shfl_xor(a2, m, 64);
            a3 += __shfl_xor(a3, m, 64);
        }
        float t = 0.0f;
#pragma unroll
        for (int ql = 0; ql < 4; ++ql) {
            t = fmaf(rdl_f(a0, ql), w2[4 * ql + 0], t);
            t = fmaf(rdl_f(a1, ql), w2[4 * ql + 1], t);
            t = fmaf(rdl_f(a2, ql), w2[4 * ql + 2], t);
            t = fmaf(rdl_f(a3, ql), w2[4 * ql + 3], t);
        }
        float r = fmaxf(fmaf(dg, t, bm), 0.0f);   // dg*(sum)@W2 + b2, relu
        outp[(long)g * 64 + lane] = __float2half(r * dg);  // pre-scaled fp16
    }
}

// ---------------- pull-gather, 64 ch fp16 (R16 exact): agg = dg * sum C ----------------
// 8 lanes x uint4 (16B) per 128B row (exactly one cache line per edge).
__global__ __launch_bounds__(256) void gather64h_k(const int* __restrict__ rowptr,
                                                   const int* __restrict__ csr_src,
                                                   const float* __restrict__ dinv,
                                                   const __half* __restrict__ hs,
                                                   __half* __restrict__ outp, int n) {
    const int g = (blockIdx.x * 256 + threadIdx.x) >> 6;
    if (g >= n) return;
    const int lane = threadIdx.x & 63;
    const int q = lane & 7;                 // uint4 chunk within 64-ch row
    const int sub = lane >> 3;              // edge subgroup 0..7
    const float dg = dinv[g];
    const int beg = rowptr[g], end = rowptr[g + 1];
    const uint4* h4 = (const uint4*)hs;     // row = 8 chunks of 16B
    float a[8];
#pragma unroll
    for (int i = 0; i < 8; ++i) a[i] = 0.f;
    if (sub == 0) {                          // self term
        uint4 v = h4[(long)g * 8 + q];
        h2acc(v.x, a[0], a[1]); h2acc(v.y, a[2], a[3]);
        h2acc(v.z, a[4], a[5]); h2acc(v.w, a[6], a[7]);
    }
    int j0 = beg;
    for (; j0 + 16 <= end; j0 += 16) {
        const int s0 = csr_src[j0 + sub];
        const int s1 = csr_src[j0 + 8 + sub];
        const uint4 v0 = h4[(long)s0 * 8 + q];
        const uint4 v1 = h4[(long)s1 * 8 + q];
        h2acc(v0.x, a[0], a[1]); h2acc(v0.y, a[2], a[3]);
        h2acc(v0.z, a[4], a[5]); h2acc(v0.w, a[6], a[7]);
        h2acc(v1.x, a[0], a[1]); h2acc(v1.y, a[2], a[3]);
        h2acc(v1.z, a[4], a[5]); h2acc(v1.w, a[6], a[7]);
    }
    for (; j0 < end; j0 += 8) {
        int idx = j0 + sub;
        if (idx < end) {
            const int s = csr_src[idx];
            const uint4 v = h4[(long)s * 8 + q];
            h2acc(v.x, a[0], a[1]); h2acc(v.y, a[2], a[3]);
            h2acc(v.z, a[4], a[5]); h2acc(v.w, a[6], a[7]);
        }
    }
#pragma unroll
    for (int m = 8; m <= 32; m <<= 1) {
#pragma unroll
        for (int i = 0; i < 8; ++i) a[i] += __shfl_xor(a[i], m, 64);
    }
    if (sub == 0) {
        uint4 w;
        w.x = packh2(a[0] * dg, a[1] * dg);
        w.y = packh2(a[2] * dg, a[3] * dg);
        w.z = packh2(a[4] * dg, a[5] * dg);
        w.w = packh2(a[6] * dg, a[7] * dg);
        ((uint4*)outp)[(long)g * 8 + q] = w;
    }
}

// ---------------- MFMA head: out = relu(agg@W3 + b3).Wfc + bfc ----------------
__global__ __launch_bounds__(256) void head_mfma_k(const __half* __restrict__ agg,
                                                   const float* __restrict__ W3,
                                                   const float* __restrict__ b3,
                                                   const float* __restrict__ Wfc,
                                                   const float* __restrict__ bfc,
                                                   float* __restrict__ out, int n) {
    __shared__ _Float16 sWf[8192];           // 16 KB, frag-layout
    const int tid = threadIdx.x;
    for (int i = tid; i < 8192; i += 256) {
        const int j = i & 7;
        const int l = (i >> 3) & 63;
        const int th = i >> 9;
        const int k = (th & 1) * 32 + ((l >> 4) << 3) + j;
        const int nn = (th >> 1) * 16 + (l & 15);
        sWf[i] = (_Float16)W3[k * 128 + nn];
    }
    __syncthreads();
    const int lane = tid & 63;
    const int wid = blockIdx.x * 4 + (tid >> 6);
    const int nWaves = gridDim.x * 4;
    const int col = lane & 15;
    const int kg = lane >> 4;
    half8 wf[16];
#pragma unroll
    for (int q2 = 0; q2 < 16; ++q2)
        wf[q2] = *((const half8*)&sWf[(q2 * 64 + lane) * 8]);
    float b3v[8], wfv[8];
#pragma unroll
    for (int t = 0; t < 8; ++t) {
        b3v[t] = b3[t * 16 + col];
        wfv[t] = Wfc[t * 16 + col];
    }
    const float bb = bfc[0];
    const int nTiles = n >> 4;               // 6250, exact
    union { uint4 u; half8 h; } cva, cvb;
    for (int tile = wid; tile < nTiles; tile += nWaves) {
        const int node0 = tile << 4;
        const uint4* rowp = (const uint4*)(agg + (long)(node0 + col) * 64);
        cva.u = rowp[kg];                     // k = kg*8 .. +8   (half 0)
        cvb.u = rowp[4 + kg];                 // k = 32 + kg*8..  (half 1)
        const half8 a0 = cva.h, a1 = cvb.h;
        f32x4 c[8];
#pragma unroll
        for (int t = 0; t < 8; ++t) {
            f32x4 z = {0.f, 0.f, 0.f, 0.f};
            c[t] = __builtin_amdgcn_mfma_f32_16x16x32_f16(a0, wf[t * 2], z, 0, 0, 0);
            c[t] = __builtin_amdgcn_mfma_f32_16x16x32_f16(a1, wf[t * 2 + 1], c[t], 0, 0, 0);
        }
        float s0 = 0.f, s1 = 0.f, s2 = 0.f, s3 = 0.f;
#pragma unroll
        for (int t = 0; t < 8; ++t) {
            s0 += fmaxf(c[t][0] + b3v[t], 0.f) * wfv[t];
            s1 += fmaxf(c[t][1] + b3v[t], 0.f) * wfv[t];
            s2 += fmaxf(c[t][2] + b3v[t], 0.f) * wfv[t];
            s3 += fmaxf(c[t][3] + b3v[t], 0.f) * wfv[t];
        }
#pragma unroll
        for (int m = 1; m <= 8; m <<= 1) {
            s0 += __shfl_xor(s0, m, 64);
            s1 += __shfl_xor(s1, m, 64);
            s2 += __shfl_xor(s2, m, 64);
            s3 += __shfl_xor(s3, m, 64);
        }
        if (col == 0) {
            const int nb = node0 + kg * 4;
            out[nb]     = s0 + bb;
            out[nb + 1] = s1 + bb;
            out[nb + 2] = s2 + bb;
            out[nb + 3] = s3 + bb;
        }
    }
}

extern "C" void kernel_launch(void* const* d_in, const int* in_sizes, int n_in,
                              void* d_out, int out_size, void* d_ws, size_t ws_size,
                              hipStream_t stream) {
    const float* x    = (const float*)d_in[0];
    const int*   ei   = (const int*)d_in[1];       // [2,E]: src = ei, dst = ei+E
    const float* W1   = (const float*)d_in[2];
    const float* b1   = (const float*)d_in[3];
    const float* W2   = (const float*)d_in[4];
    const float* b2   = (const float*)d_in[5];
    const float* W3   = (const float*)d_in[6];
    const float* b3   = (const float*)d_in[7];
    const float* Wfc  = (const float*)d_in[8];
    const float* bfc  = (const float*)d_in[9];
    float* out = (float*)d_out;

    const int* src = ei;
    const int* dst = ei + NE;

    // workspace layout (16B-aligned offsets; 4B units):
    // dinv[N] | rowptr[N+8] | mat[NBLK*NB2] | ofsT[NBLK*NB2] | colTotal[512]
    // | bucketBase[512] | csr_src[E+64] | bucketed[E] u32
    // | A_h[16N] fp16 | B_h[16N] fp16 | C_h[64N] fp16 | agg_h[64N] fp16
    float* dinv        = (float*)d_ws;
    int*   rowptr      = (int*)(dinv + NN);
    int*   mat         = rowptr + NN + 8;
    int*   ofsT        = mat + NBLK * NB2 + 4;
    int*   colTotal    = ofsT + NBLK * NB2 + 4;
    int*   bucketBase  = colTotal + 512;
    int*   csr_src     = bucketBase + 512;
    unsigned* bucketed = (unsigned*)(csr_src + NE + 64);
    __half* A_h        = (__half*)(bucketed + NE);
    __half* B_h        = A_h + (long)NN * 16;
    __half* C_h        = B_h + (long)NN * 16;
    __half* agg_h      = C_h + (long)NN * 64;

    const int T = 256;

    // ---- CSR build (atomic-free) + MFMA gemm1 overlapped ----
    const int gemmBlocks = (NN + 63) / 64;             // 1563
    count_gemm1_k<<<NBLK + gemmBlocks, T, 0, stream>>>(dst, mat, x, W1, A_h, NN);
    colscan_k<<<NB2, 64, 0, stream>>>(mat, ofsT, colTotal);
    p2_scatter_k<<<NBLK, 512, 0, stream>>>(src, dst, ofsT, mat, colTotal, bucketBase, bucketed);
    p3_csr_k<<<NB2, 512, 0, stream>>>(bucketed, bucketBase, rowptr, dinv, csr_src, A_h);

    // ---- B = dinv * relu(dg*(sum A) + b1)  (pre-scaled r1, 16ch fp16) ----
    gather16h_k<<<2048, T, 0, stream>>>(rowptr, csr_src, dinv, A_h, b1, B_h, NN);
    // ---- C = dinv * relu(dg*(sum B)@W2 + b2)  (pre-scaled r2, 64ch fp16) ----
    g16gemm2h_k<<<2048, T, 0, stream>>>(rowptr, csr_src, dinv, B_h, W2, b2, C_h, NN);
    // ---- agg(64ch fp16) = dg * sum C ----
    gather64h_k<<<(NN + 3) / 4, T, 0, stream>>>(rowptr, csr_src, dinv, C_h, agg_h, NN);
    // ---- head: out = relu(agg@W3 + b3).Wfc + bfc  (MFMA) ----
    head_mfma_k<<<256, T, 0, stream>>>(agg_h, W3, b3, Wfc, bfc, out, NN);
}